// Round 3
// baseline (648.705 us; speedup 1.0000x reference)
//
#include <hip/hip_runtime.h>

// Problem: BATCH=64, NFILT=512, T=1024, FFT over first 512 samples, 257 bins.
//   bc = (fc/Q)*0.5*sqrt(2pi)/FS ; n = t+1
//   y[b,f,t] = exp(-(bc*n)^2) * cos(2pi*fc/FS*n)
//   maxsq[f] = max_{b,k} |DFT_512(y[b,f,0:512])[k]|^2
//   out[b,f,t] = y[b,f,1023-t] * rsqrt(maxsq[f])
//
// R13: FUSED single kernel (producer/consumer, "last one writes").
//   Timing solved from R6..R12 deltas: fixed harness overhead C~127us,
//   k_maxfft~10us, k_write~25us. Only winnable term is m+w+gap~35us; floor
//   is max(store BW 21.6us, compute ~10us). Fusion overlaps them.
//   - Producer: identical math to R12 k_maxfft (bit-identical mx), but
//     per-filter max via uint-punned atomicMax into ws[f] (values >= 0,
//     uint order == float order => bitwise-identical batch max).
//   - done[f] counter (atomicAdd, device scope); the 64th producer's BLOCK
//     writes all 64 rows of f (R12 k_write row formula, bit-identical).
//   - No spinning anywhere => no deadlock regardless of scheduling.
//   - ws[0:512]=maxes, ws[512:1024]=done; zeroed by 4KB hipMemsetAsync.
//   - Cross-XCD: atomics + __threadfence (per-XCD L2 not coherent).

#define BCOEF_K 7.8332133582218756e-05f  // 0.5*sqrt(2*pi)/16000
#define INV_FS  6.25e-05f                // 1/16000
#define TWO_PI  6.28318530717958647692f
#define PI_F    3.14159265358979323846f
#define SIGK_K  115.2309f                // sqrt(2)*512/(2*pi)
#define KAPPA   1.3f                     // pruning safety factor
#define FULL_FC 700.0f                   // below this fc, evaluate all 64 b

typedef float vf4 __attribute__((ext_vector_type(4)));

__device__ __forceinline__ float fast_carrier(float fcn, float n) {
  float rev = fcn * n;
  float fr  = rev - floorf(rev);
  return __cosf(TWO_PI * fr);
}
__device__ __forceinline__ float fast_env(float x) { return __expf(-x * x); }

// ---------------------------------------------------------------------------
// Fused kernel: block = 4 waves; wave w owns signal sig = blk*4+w = bb*512+f.
// Phase 1 (producer): generate truncated signal in private LDS row, windowed
// Goertzel, lane-reduce -> mx. atomicMax into ws[f]; atomicAdd done[f].
// Phase 2 (writer): the block containing the 64th producer of f writes all
// 64 output rows of f cooperatively (4 waves x 16 rows).
// ---------------------------------------------------------------------------
__global__ __launch_bounds__(256) void k_fused(const float* __restrict__ Q,
                                               const float* __restrict__ fc,
                                               float* __restrict__ ws,
                                               float* __restrict__ out) {
  const int tid  = threadIdx.x;
  const int w    = tid >> 6;           // wave 0..3
  const int lane = tid & 63;
  const int sig  = blockIdx.x * 4 + w; // bb*512 + f
  const int f    = sig & 511;
  const int bb   = sig >> 9;

  __shared__ __align__(16) float ybuf[4][512];
  __shared__ float inv_s[4];
  __shared__ int   fwon[4];

  unsigned* const wmax = (unsigned*)ws;        // [512] uint-punned f32 maxes
  int*      const done = (int*)(ws + 512);     // [512] completion counters

  const float fcv = fc[f];
  const float q   = Q[bb * 512 + f];
  const float bc  = (fcv / q) * BCOEF_K;
  const float fcn = fcv * INV_FS;

  // --- pruning decision (same predicate as R10/R12) ---
  float qq = Q[lane * 512 + f];        // lane = batch index (Q is L2-hot)
  #pragma unroll
  for (int d = 32; d > 0; d >>= 1) qq = fmaxf(qq, __shfl_xor(qq, d));
  const bool pruned = (fcv >= FULL_FC && bc * qq > KAPPA * fcv * BCOEF_K);

  float mx = 0.0f;
  if (!pruned) {
    // --- effective length: env < e^-16 beyond nstar = 4/bc (wave-uniform) ---
    const float nstar = 4.0f / bc;
    const int   N_eff = (nstar >= 510.0f) ? 512 : ((int)nstar + 2);
    const int   jmax  = (N_eff + 3) >> 2;    // float4 groups Goertzel reads
    const int   n4    = jmax << 2;           // samples to generate

    // --- lane-strided generation ---
    float* yw = &ybuf[w][0];
    const int nit_g = (n4 + 63) >> 6;        // 1..8, wave-uniform
    for (int r = 0; r < nit_g; ++r) {
      const int idx = (r << 6) + lane;       // t index; n = idx+1
      const float n = (float)(idx + 1);
      const float v = fast_env(bc * n) * fast_carrier(fcn, n);
      if (idx < n4) yw[idx] = v;             // masked tail store
    }
    asm volatile("s_waitcnt lgkmcnt(0)" ::: "memory");  // wave-private row

    // --- spectral-peak window (wave-uniform) ---
    const int kci  = (int)(fcn * 512.0f + 0.5f);
    const int W    = (int)(2.0f * (bc * SIGK_K)) + 6;
    const int k_lo = max(0, kci - W);
    const int k_hi = min(256, kci + W);
    const int nit  = ((k_hi - k_lo) >> 6) + 1;  // 1..5 iterations

    const float4* y4 = (const float4*)yw;       // wave-uniform broadcasts
    for (int it = 0; it < nit; ++it) {
      const int   k = min(k_lo + (it << 6) + lane, k_hi);
      const float c = 2.0f * cosf((float)k * (PI_F / 256.0f));
      float s1 = 0.0f, s2 = 0.0f;
      #pragma unroll 4
      for (int j = 0; j < jmax; ++j) {
        const float4 x = y4[j];
        float s;
        s = fmaf(c, s1, x.x - s2); s2 = s1; s1 = s;
        s = fmaf(c, s1, x.y - s2); s2 = s1; s1 = s;
        s = fmaf(c, s1, x.z - s2); s2 = s1; s1 = s;
        s = fmaf(c, s1, x.w - s2); s2 = s1; s1 = s;
      }
      mx = fmaxf(mx, fmaf(s1, s1, fmaf(s2, s2, -(c * s1 * s2))));
    }
    #pragma unroll
    for (int d = 32; d > 0; d >>= 1) mx = fmaxf(mx, __shfl_xor(mx, d));
  }

  // --- publish + completion count (device-scope; cross-XCD safe) ---
  int old = 0;
  if (lane == 0) {
    if (!pruned) atomicMax(&wmax[f], __float_as_uint(mx));  // no-op if pruned
    __threadfence();                    // release: wmax visible before count
    old = atomicAdd(&done[f], 1);
  }
  old = __shfl(old, 0);
  const bool winner = (old == 63);      // unique per f

  float inv = 0.0f;
  if (winner) {
    __threadfence();                    // acquire side
    unsigned mu = __hip_atomic_load(&wmax[f], __ATOMIC_ACQUIRE,
                                    __HIP_MEMORY_SCOPE_AGENT);
    inv = rsqrtf(__uint_as_float(mu));
  }
  if (lane == 0) { inv_s[w] = inv; fwon[w] = winner ? f : -1; }
  __syncthreads();

  // --- cooperative write of each won filter: 4 waves x 16 rows ---
  for (int w2 = 0; w2 < 4; ++w2) {
    const int fw = fwon[w2];
    if (fw < 0) continue;
    const float invw = inv_s[w2];
    const float fcw  = fc[fw];
    const float fcn2 = fcw * INV_FS;
    for (int i = 0; i < 16; ++i) {
      const int bb2 = (w << 4) + i;
      const float q2  = Q[bb2 * 512 + fw];
      const float bc2 = (fcw / q2) * BCOEF_K;
      const float ns2 = 4.0f / bc2;
      vf4* __restrict__ orow = (vf4*)out + ((size_t)(bb2 * 512 + fw)) * 256;
      #pragma unroll
      for (int r = 0; r < 4; ++r) {
        const int qi = (r << 6) + lane;   // quad index 0..255
        const int t0 = qi << 2;
        vf4 v = {0.0f, 0.0f, 0.0f, 0.0f};
        if ((float)(1021 - t0) <= ns2) {
          const float n0 = (float)(1024 - t0);
          const float n1 = (float)(1023 - t0);
          const float n2 = (float)(1022 - t0);
          const float n3 = (float)(1021 - t0);
          v.x = fast_env(bc2 * n0) * fast_carrier(fcn2, n0) * invw;
          v.y = fast_env(bc2 * n1) * fast_carrier(fcn2, n1) * invw;
          v.z = fast_env(bc2 * n2) * fast_carrier(fcn2, n2) * invw;
          v.w = fast_env(bc2 * n3) * fast_carrier(fcn2, n3) * invw;
        }
        orow[qi] = v;                     // coalesced 1KB/wave store
      }
    }
  }
}

// ---------------------------------------------------------------------------
extern "C" void kernel_launch(void* const* d_in, const int* in_sizes, int n_in,
                              void* d_out, int out_size, void* d_ws, size_t ws_size,
                              hipStream_t stream) {
  const float* Q  = (const float*)d_in[0];   // [64, 512] f32
  const float* fc = (const float*)d_in[1];   // [512] f32
  float* out      = (float*)d_out;           // [64, 512, 1024] f32
  float* ws       = (float*)d_ws;            // [512 maxes][512 counters]

  hipMemsetAsync(d_ws, 0, 1024 * sizeof(float), stream);  // zero maxes+counters
  k_fused<<<64 * 512 / 4, 256, 0, stream>>>(Q, fc, ws, out);
}

// Round 5
// 165.947 us; speedup vs baseline: 3.9091x; 3.9091x over previous
//
#include <hip/hip_runtime.h>

// Problem: BATCH=64, NFILT=512, T=1024, FFT over first 512 samples, 257 bins.
//   bc = (fc/Q)*0.5*sqrt(2pi)/FS ; n = t+1
//   y[b,f,t] = exp(-(bc*n)^2) * cos(2pi*fc/FS*n)
//   maxsq[f] = max_{b,k} |DFT_512(y[b,f,0:512])[k]|^2
//   out[b,f,t] = y[b,f,1023-t] * rsqrt(maxsq[f])
//
// R15 = R14 byte-identical resubmission (Round-4 bench died with
//   "MI355X container failed twice" — infra, no counters; R14 has no
//   hang-capable constructs: no atomics, no cross-block sync, no spins).
//
// R14: block-per-filter fusion, NO cross-block sync (R13 post-mortem:
//   "last one writes" concentrated 128 MiB of stores + recompute on 512
//   winner blocks -> 16x parallelism collapse, 549us, VALUBusy 4.4%).
//   Here: grid=512 blocks x 512 threads (8 waves). Block f:
//     phase 1: wave w produces signals bb = 8*i+w (i=0..7) serially —
//              exact R12 k_maxfft math (pruning, truncation, windowed
//              Goertzel) -> smax[bb] in LDS.  __syncthreads.
//     reduce:  64-way fmaxf (exact max => bit-identical inv to R12).
//     phase 2: wave w writes rows bb = 8*i+w with exact R12 k_write
//              row formula. 8 rows/wave, 4 quads/lane per row.
//   Benefits: single kernel (no gap), writes start as soon as each block's
//   own filter is done (overlap with other blocks' compute), store work
//   evenly spread (2 blocks/CU, 512KB/CU). VALU evidence (24us aggregate)
//   says compute hides under the 21.6us store-BW floor.
//   Prediction: 130-150us total; WRITE_SIZE ~131072 KB single dispatch.

#define BCOEF_K 7.8332133582218756e-05f  // 0.5*sqrt(2*pi)/16000
#define INV_FS  6.25e-05f                // 1/16000
#define TWO_PI  6.28318530717958647692f
#define PI_F    3.14159265358979323846f
#define SIGK_K  115.2309f                // sqrt(2)*512/(2*pi)
#define KAPPA   1.3f                     // pruning safety factor
#define FULL_FC 700.0f                   // below this fc, evaluate all 64 b

typedef float vf4 __attribute__((ext_vector_type(4)));

__device__ __forceinline__ float fast_carrier(float fcn, float n) {
  float rev = fcn * n;
  float fr  = rev - floorf(rev);
  return __cosf(TWO_PI * fr);
}
__device__ __forceinline__ float fast_env(float x) { return __expf(-x * x); }

// ---------------------------------------------------------------------------
// One block per filter f. 8 waves; wave w handles signals/rows bb = 8*i + w.
// ---------------------------------------------------------------------------
__global__ __launch_bounds__(512) void k_filter(const float* __restrict__ Q,
                                                const float* __restrict__ fc,
                                                float* __restrict__ out) {
  const int tid  = threadIdx.x;
  const int w    = tid >> 6;           // wave 0..7
  const int lane = tid & 63;
  const int f    = blockIdx.x;         // filter 0..511

  __shared__ __align__(16) float ybuf[8][512];
  __shared__ float smax[64];

  const float fcv = fc[f];
  const float fcn = fcv * INV_FS;

  // batch-max Q for the pruning predicate (same tree as R12)
  float qq = Q[lane * 512 + f];
  #pragma unroll
  for (int d = 32; d > 0; d >>= 1) qq = fmaxf(qq, __shfl_xor(qq, d));

  float* const yw = &ybuf[w][0];            // wave-private LDS row
  const float4* const y4 = (const float4*)yw;

  // ---------------- phase 1: produce 8 signals per wave ----------------
  for (int i = 0; i < 8; ++i) {
    const int   bb = (i << 3) + w;
    const float q  = Q[bb * 512 + f];
    const float bc = (fcv / q) * BCOEF_K;
    float mx = 0.0f;

    if (!(fcv >= FULL_FC && bc * qq > KAPPA * fcv * BCOEF_K)) {   // survivor
      // effective length: env < e^-16 beyond nstar = 4/bc (wave-uniform)
      const float nstar = 4.0f / bc;
      const int   N_eff = (nstar >= 510.0f) ? 512 : ((int)nstar + 2);
      const int   jmax  = (N_eff + 3) >> 2;   // float4 groups Goertzel reads
      const int   n4    = jmax << 2;          // samples to generate

      // previous signal's LDS reads must drain before overwrite (wave-local)
      asm volatile("s_waitcnt lgkmcnt(0)" ::: "memory");

      const int nit_g = (n4 + 63) >> 6;       // 1..8, wave-uniform
      for (int r = 0; r < nit_g; ++r) {
        const int idx = (r << 6) + lane;      // t index; n = idx+1
        const float n = (float)(idx + 1);
        const float v = fast_env(bc * n) * fast_carrier(fcn, n);
        if (idx < n4) yw[idx] = v;            // masked tail store
      }
      asm volatile("s_waitcnt lgkmcnt(0)" ::: "memory");

      // spectral-peak window (wave-uniform)
      const int kci  = (int)(fcn * 512.0f + 0.5f);
      const int W    = (int)(2.0f * (bc * SIGK_K)) + 6;
      const int k_lo = max(0, kci - W);
      const int k_hi = min(256, kci + W);
      const int nit  = ((k_hi - k_lo) >> 6) + 1;  // 1..5

      for (int it = 0; it < nit; ++it) {
        const int   k = min(k_lo + (it << 6) + lane, k_hi);  // dup harmless
        const float c = 2.0f * cosf((float)k * (PI_F / 256.0f));
        float s1 = 0.0f, s2 = 0.0f;
        #pragma unroll 4
        for (int j = 0; j < jmax; ++j) {      // wave-uniform trip count
          const float4 x = y4[j];             // wave-uniform broadcast read
          float s;
          s = fmaf(c, s1, x.x - s2); s2 = s1; s1 = s;
          s = fmaf(c, s1, x.y - s2); s2 = s1; s1 = s;
          s = fmaf(c, s1, x.z - s2); s2 = s1; s1 = s;
          s = fmaf(c, s1, x.w - s2); s2 = s1; s1 = s;
        }
        mx = fmaxf(mx, fmaf(s1, s1, fmaf(s2, s2, -(c * s1 * s2))));
      }
      #pragma unroll
      for (int d = 32; d > 0; d >>= 1) mx = fmaxf(mx, __shfl_xor(mx, d));
    }
    if (lane == 0) smax[bb] = mx;             // pruned -> 0.0 (same as R12)
  }

  __syncthreads();

  // ---------------- block max -> inv (bit-identical: max is exact) -------
  float mxall = smax[lane];
  #pragma unroll
  for (int d = 32; d > 0; d >>= 1) mxall = fmaxf(mxall, __shfl_xor(mxall, d));
  const float inv = rsqrtf(mxall);

  // ---------------- phase 2: write 8 rows per wave (exact R12 formula) ---
  for (int i = 0; i < 8; ++i) {
    const int   bb = (i << 3) + w;
    const float q  = Q[bb * 512 + f];
    const float bc = (fcv / q) * BCOEF_K;
    const float ns = 4.0f / bc;
    vf4* __restrict__ orow = (vf4*)out + (size_t)(bb * 512 + f) * 256;
    #pragma unroll
    for (int r = 0; r < 4; ++r) {
      const int qi = (r << 6) + lane;   // quad index 0..255
      const int t0 = qi << 2;
      vf4 v = {0.0f, 0.0f, 0.0f, 0.0f};
      // quad covers n = 1021-t0 .. 1024-t0; all dead iff smallest n > nstar
      if ((float)(1021 - t0) <= ns) {
        const float n0 = (float)(1024 - t0);
        const float n1 = (float)(1023 - t0);
        const float n2 = (float)(1022 - t0);
        const float n3 = (float)(1021 - t0);
        v.x = fast_env(bc * n0) * fast_carrier(fcn, n0) * inv;
        v.y = fast_env(bc * n1) * fast_carrier(fcn, n1) * inv;
        v.z = fast_env(bc * n2) * fast_carrier(fcn, n2) * inv;
        v.w = fast_env(bc * n3) * fast_carrier(fcn, n3) * inv;
      }
      orow[qi] = v;                     // coalesced 1KB/wave cached store
    }
  }
}

// ---------------------------------------------------------------------------
extern "C" void kernel_launch(void* const* d_in, const int* in_sizes, int n_in,
                              void* d_out, int out_size, void* d_ws, size_t ws_size,
                              hipStream_t stream) {
  const float* Q  = (const float*)d_in[0];   // [64, 512] f32
  const float* fc = (const float*)d_in[1];   // [512] f32
  float* out      = (float*)d_out;           // [64, 512, 1024] f32
  (void)d_ws; (void)ws_size;                 // no workspace needed

  k_filter<<<512, 512, 0, stream>>>(Q, fc, out);
}